// Round 1
// baseline (11.205 us; speedup 1.0000x reference)
//
#include <hip/hip_runtime.h>
#include <hip/hip_bf16.h>
#include <math.h>

// 4-wire quantum circuit simulator, B=262144 batch.
// State = 16 complex amplitudes per batch element, held entirely in registers.
// Wire w <-> bit (3-w) of the flat state index (wire 0 = MSB).

#define NWIRES 4

// Ry(t) = [[c,-s],[s,c]], real.  a' = c*a - s*b ; b' = s*a + c*b
template<int W>
__device__ __forceinline__ void apply_ry(float (&sr)[16], float (&si)[16], float c, float s) {
    constexpr int bit = 1 << (3 - W);
    #pragma unroll
    for (int i = 0; i < 16; ++i) {
        if (!(i & bit)) {
            constexpr int dummy = 0; (void)dummy;
            const int j = i | bit;
            float ar = sr[i], ai = si[i], br = sr[j], bi = si[j];
            sr[i] = c * ar - s * br;
            si[i] = c * ai - s * bi;
            sr[j] = s * ar + c * br;
            si[j] = s * ai + c * bi;
        }
    }
}

// Rx(t) = [[c,-i s],[-i s,c]].
// a' = c*a - i s*b  -> re: c*ar + s*bi ; im: c*ai - s*br
// b' = -i s*a + c*b -> re: s*ai + c*br ; im: -s*ar + c*bi
template<int W>
__device__ __forceinline__ void apply_rx(float (&sr)[16], float (&si)[16], float c, float s) {
    constexpr int bit = 1 << (3 - W);
    #pragma unroll
    for (int i = 0; i < 16; ++i) {
        if (!(i & bit)) {
            const int j = i | bit;
            float ar = sr[i], ai = si[i], br = sr[j], bi = si[j];
            sr[i] = c * ar + s * bi;
            si[i] = c * ai - s * br;
            sr[j] = c * br + s * ai;
            si[j] = c * bi - s * ar;
        }
    }
}

// Rz(t) = diag(e^{-i t/2}, e^{+i t/2}); c=cos(t/2), s=sin(t/2)
// a' = (c - i s)*a -> re: c*ar + s*ai ; im: c*ai - s*ar
// b' = (c + i s)*b -> re: c*br - s*bi ; im: c*bi + s*br
template<int W>
__device__ __forceinline__ void apply_rz(float (&sr)[16], float (&si)[16], float c, float s) {
    constexpr int bit = 1 << (3 - W);
    #pragma unroll
    for (int i = 0; i < 16; ++i) {
        if (!(i & bit)) {
            const int j = i | bit;
            float ar = sr[i], ai = si[i], br = sr[j], bi = si[j];
            sr[i] = c * ar + s * ai;
            si[i] = c * ai - s * ar;
            sr[j] = c * br - s * bi;
            si[j] = c * bi + s * br;
        }
    }
}

// CNOT control wire C, target wire C+1: where control bit set, swap target bit.
template<int C>
__device__ __forceinline__ void apply_cnot(float (&sr)[16], float (&si)[16]) {
    constexpr int cb = 1 << (3 - C);
    constexpr int tb = 1 << (2 - C);
    #pragma unroll
    for (int i = 0; i < 16; ++i) {
        if ((i & cb) && !(i & tb)) {
            const int j = i | tb;
            float t;
            t = sr[i]; sr[i] = sr[j]; sr[j] = t;
            t = si[i]; si[i] = si[j]; si[j] = t;
        }
    }
}

__global__ __launch_bounds__(256) void qsim_kernel(
        const float* __restrict__ x,
        const float* __restrict__ y,
        const float* __restrict__ theta,
        float* __restrict__ out,
        int B) {
    int b = blockIdx.x * blockDim.x + threadIdx.x;
    if (b >= B) return;

    // ---- load per-batch inputs ----
    float4 xv = reinterpret_cast<const float4*>(x)[b];
    float y0  = y[4 * b];   // only y[:,0] affects the output (see derivation)

    // ---- encoder Ry(x_w)|0> = product state (real) ----
    float c0, s0, c1, s1, c2, s2, c3, s3;
    __sincosf(0.5f * xv.x, &s0, &c0);
    __sincosf(0.5f * xv.y, &s1, &c1);
    __sincosf(0.5f * xv.z, &s2, &c2);
    __sincosf(0.5f * xv.w, &s3, &c3);

    float sr[16], si[16];
    #pragma unroll
    for (int i = 0; i < 16; ++i) {
        float p = ((i & 8) ? s0 : c0)
                * ((i & 4) ? s1 : c1)
                * ((i & 2) ? s2 : c2)
                * ((i & 1) ? s3 : c3);
        sr[i] = p;
        si[i] = 0.0f;
    }

    // ---- fixed 20-op layer; theta is uniform across the batch ----
    // op i: i%4==3 -> CNOT((i/4)%3); else wire=(7i+3)%4, kind i%4: 0=RX,1=RY,2=RZ
    float tc, ts;
    #define ROT(IDX, FN, W) do { \
        __sincosf(0.5f * theta[IDX], &ts, &tc); \
        FN<W>(sr, si, tc, ts); \
    } while (0)

    ROT(0,  apply_rx, 3);
    ROT(1,  apply_ry, 2);
    ROT(2,  apply_rz, 1);
    apply_cnot<0>(sr, si);
    ROT(4,  apply_rx, 3);
    ROT(5,  apply_ry, 2);
    ROT(6,  apply_rz, 1);
    apply_cnot<1>(sr, si);
    ROT(8,  apply_rx, 3);
    ROT(9,  apply_ry, 2);
    ROT(10, apply_rz, 1);
    apply_cnot<2>(sr, si);
    ROT(12, apply_rx, 3);
    ROT(13, apply_ry, 2);
    ROT(14, apply_rz, 1);
    apply_cnot<0>(sr, si);
    ROT(16, apply_rx, 3);
    ROT(17, apply_ry, 2);
    ROT(18, apply_rz, 1);
    apply_cnot<1>(sr, si);
    #undef ROT

    // ---- measurement: z0 = cos(y0)*<Z0> + sin(y0)*<X0>, out = |z0| ----
    // (second encoder Ry(-y_w) on wires 1..3 commutes with Z0 and cancels;
    //  Ry(-y0)^† Z0 Ry(-y0) = cos(y0) Z0 + sin(y0) X0)
    float zacc = 0.0f, xacc = 0.0f;
    #pragma unroll
    for (int i = 0; i < 8; ++i) {
        float p0 = sr[i] * sr[i] + si[i] * si[i];
        float p1 = sr[i + 8] * sr[i + 8] + si[i + 8] * si[i + 8];
        zacc += p0 - p1;
        xacc += sr[i] * sr[i + 8] + si[i] * si[i + 8];
    }
    xacc *= 2.0f;

    float cy, sy;
    __sincosf(y0, &sy, &cy);
    out[b] = fabsf(cy * zacc + sy * xacc);
}

extern "C" void kernel_launch(void* const* d_in, const int* in_sizes, int n_in,
                              void* d_out, int out_size, void* d_ws, size_t ws_size,
                              hipStream_t stream) {
    const float* x     = (const float*)d_in[0];
    const float* y     = (const float*)d_in[1];
    const float* theta = (const float*)d_in[2];
    float* out = (float*)d_out;

    int B = out_size;  // 262144
    int block = 256;
    int grid = (B + block - 1) / block;
    qsim_kernel<<<grid, block, 0, stream>>>(x, y, theta, out, B);
}